// Round 1
// baseline (507.122 us; speedup 1.0000x reference)
//
#include <hip/hip_runtime.h>
#include <math.h>

// NoisyTopKRouter: out0 = softmax over top-2 of (x @ route_w^T + route_b) scattered
// into [16384,64]; out1 = top-2 indices (written as floats).
// noise / noise_w / noise_b are dead inputs (reference computes noisy logits but
// never uses them in the output).

#define TOKENS 16384
#define EMB    4096
#define NE     64
#define TB     16            // tokens per block
#define NWAVE  4
#define KQ     (EMB / NWAVE) // 1024 K per wave (split-K within block)
#define KR     64            // K per register segment
#define NSEG   (KQ / KR)     // 16

// d_ws layout: W_t[4096][64] f32 = 1 MB
__global__ __launch_bounds__(256) void wt_transpose_kernel(const float* __restrict__ w,
                                                           float* __restrict__ wt) {
    int idx = blockIdx.x * 256 + threadIdx.x;   // over 4096*64, coalesced writes
    int e = idx & (NE - 1);
    int k = idx >> 6;
    wt[idx] = w[e * EMB + k];                   // uncoalesced reads, 1 MB, L2-absorbed
}

__global__ __launch_bounds__(256, 4) void router_kernel(const float* __restrict__ x,
                                                        const float* __restrict__ wt,
                                                        const float* __restrict__ rb,
                                                        float* __restrict__ out) {
    __shared__ float red[NWAVE][TB][NE];        // 16 KB cross-wave partials
    __shared__ float s_p1[TB], s_p2[TB];
    __shared__ int   s_i1[TB], s_i2[TB];

    const int tid  = threadIdx.x;
    const int lane = tid & 63;                                     // = expert id
    const int wq   = __builtin_amdgcn_readfirstlane(tid >> 6);     // wave id, SGPR
    const long tok0 = (long)blockIdx.x * TB;

    float acc[TB];
#pragma unroll
    for (int t = 0; t < TB; ++t) acc[t] = 0.f;

    const int kbase = wq * KQ;
    for (int seg = 0; seg < NSEG; ++seg) {
        const int k0 = kbase + seg * KR;
        // W-stationary: lane e holds W_t[k0..k0+63][e] in VGPRs (coalesced loads)
        float wr[KR];
#pragma unroll
        for (int j = 0; j < KR; ++j) wr[j] = wt[(k0 + j) * NE + lane];
        // x row addresses are wave-uniform -> s_load; FMA reads SGPR + VGPR
#pragma unroll
        for (int t = 0; t < TB; ++t) {
            const float* __restrict__ xr = x + (tok0 + t) * EMB + k0;
            float a = acc[t];
#pragma unroll
            for (int j = 0; j < KR; ++j) a = fmaf(xr[j], wr[j], a);
            acc[t] = a;
        }
    }

    // cross-wave reduction (pairwise) + bias
#pragma unroll
    for (int t = 0; t < TB; ++t) red[wq][t][lane] = acc[t];
    __syncthreads();
    {
        const int e  = tid & 63;
        const int tg = tid >> 6;
        const float b = rb[e];
#pragma unroll
        for (int i = 0; i < 4; ++i) {
            const int t = tg + i * 4;
            float v = (red[0][t][e] + red[1][t][e]) + (red[2][t][e] + red[3][t][e]) + b;
            red[0][t][e] = v;   // each (t,e) cell owned by exactly one thread
        }
    }
    __syncthreads();

    // top-2 (jax tie rule: ascending scan, strict >) + 2-way softmax
    if (tid < TB) {
        const int t = tid;
        float m1 = -INFINITY, m2 = -INFINITY;
        int i1 = 0, i2 = 0;
        for (int e = 0; e < NE; ++e) {
            float v = red[0][t][e];
            if (v > m1)      { m2 = m1; i2 = i1; m1 = v; i1 = e; }
            else if (v > m2) { m2 = v;  i2 = e; }
        }
        const float ed = expf(m2 - m1);       // <= 1
        const float p1 = 1.f / (1.f + ed);
        s_p1[t] = p1;
        s_p2[t] = 1.f - p1;
        s_i1[t] = i1;
        s_i2[t] = i2;
    }
    __syncthreads();

    // write router_output rows (must write every element: zeros included)
    {
        const int t  = tid >> 4;       // 16 threads per token
        const int c  = tid & 15;       // float4 slot
        const int e0 = c * 4;
        const int i1 = s_i1[t], i2 = s_i2[t];
        const float p1 = s_p1[t], p2 = s_p2[t];
        float v[4];
#pragma unroll
        for (int j = 0; j < 4; ++j) {
            const int e = e0 + j;
            v[j] = (e == i1) ? p1 : ((e == i2) ? p2 : 0.f);
        }
        float4 v4 = make_float4(v[0], v[1], v[2], v[3]);
        *reinterpret_cast<float4*>(out + (tok0 + t) * NE + e0) = v4;
    }
    // indices as floats, after the 16384*64 router block
    if (tid < TB) {
        float* idxo = out + (long)TOKENS * NE + (tok0 + tid) * 2;
        idxo[0] = (float)s_i1[tid];
        idxo[1] = (float)s_i2[tid];
    }
}

extern "C" void kernel_launch(void* const* d_in, const int* in_sizes, int n_in,
                              void* d_out, int out_size, void* d_ws, size_t ws_size,
                              hipStream_t stream) {
    const float* x       = (const float*)d_in[0];
    // d_in[1] = noise (unused)
    const float* route_w = (const float*)d_in[2];
    const float* route_b = (const float*)d_in[3];
    // d_in[4], d_in[5] = noise_w, noise_b (unused)
    float* wt  = (float*)d_ws;          // 1 MB scratch
    float* out = (float*)d_out;

    hipLaunchKernelGGL(wt_transpose_kernel, dim3((EMB * NE) / 256), dim3(256), 0, stream,
                       route_w, wt);
    hipLaunchKernelGGL(router_kernel, dim3(TOKENS / TB), dim3(256), 0, stream,
                       x, wt, route_b, out);
}

// Round 2
// 265.692 us; speedup vs baseline: 1.9087x; 1.9087x over previous
//
#include <hip/hip_runtime.h>
#include <math.h>

// NoisyTopKRouter: out0 = softmax over top-2 of (x @ route_w^T + route_b) scattered
// into [16384,64]; out1 = top-2 indices (as floats). noise inputs are dead.
//
// R1: x goes global -> LDS (global_load_lds, 16B, double-buffered, coalesced)
// -> broadcast ds_read_b128. w stays in VGPRs (64 per segment). Lane = expert.

#define TOKENS 16384
#define EMB    4096
#define NE     64
#define TB     16            // tokens per block
#define NWAVE  4
#define KQ     (EMB / NWAVE) // 1024 K per wave (split-K within block)
#define KR     64            // K per register segment
#define NSEG   (KQ / KR)     // 16

#define GLOAD_LDS16(g, l)                                                      \
    __builtin_amdgcn_global_load_lds(                                          \
        (const __attribute__((address_space(1))) void*)(g),                    \
        (__attribute__((address_space(3))) void*)(l), 16, 0, 0)

// d_ws: W_t[4096][64] f32 = 1 MB (L2-resident; each XCD caches its own copy)
__global__ __launch_bounds__(256) void wt_transpose_kernel(const float* __restrict__ w,
                                                           float* __restrict__ wt) {
    int idx = blockIdx.x * 256 + threadIdx.x;
    int e = idx & (NE - 1);
    int k = idx >> 6;
    wt[idx] = w[e * EMB + k];
}

__global__ __launch_bounds__(256, 4) void router_kernel(const float* __restrict__ x,
                                                        const float* __restrict__ wt,
                                                        const float* __restrict__ rb,
                                                        float* __restrict__ out) {
    // xbuf[2][NWAVE][TB][KR] = 32 KB; after the K-loop, buf0 region is reused
    // as red[NWAVE][TB][NE] (16 KB) for the cross-wave reduction.
    __shared__ float smem[2 * NWAVE * TB * KR];
    __shared__ float s_p1[TB], s_p2[TB];
    __shared__ int   s_i1[TB], s_i2[TB];

    const int tid  = threadIdx.x;
    const int lane = tid & 63;                                  // = expert id
    const int wq   = __builtin_amdgcn_readfirstlane(tid >> 6);  // wave id
    const long tok0 = (long)blockIdx.x * TB;

    // per-lane staging coordinates: 4 global_load_lds(16B) per wave per seg
    const int st_t = lane >> 4;        // + r*4
    const int st_j = (lane & 15) * 4;

    float acc[TB];
#pragma unroll
    for (int t = 0; t < TB; ++t) acc[t] = 0.f;

    // prologue: stage seg 0 into buf 0
#pragma unroll
    for (int r = 0; r < 4; ++r) {
        const float* g = x + (tok0 + r * 4 + st_t) * EMB + wq * KQ + 0 * KR + st_j;
        float* l = &smem[((0 * NWAVE + wq) * TB + r * 4) * KR];
        GLOAD_LDS16(g, l);
    }
    __syncthreads();

    for (int s = 0; s < NSEG; ++s) {
        const int b = s & 1;
        const int k0 = wq * KQ + s * KR;

        // 1) issue w loads for this seg FIRST (vector path, coalesced 256B/row)
        float wr[KR];
#pragma unroll
        for (int j = 0; j < KR; ++j) wr[j] = wt[(k0 + j) * NE + lane];

        // 2) then issue next-seg x staging (stays in flight behind the wr wait)
        if (s + 1 < NSEG) {
#pragma unroll
            for (int r = 0; r < 4; ++r) {
                const float* g = x + (tok0 + r * 4 + st_t) * EMB + wq * KQ + (s + 1) * KR + st_j;
                float* l = &smem[(((b ^ 1) * NWAVE + wq) * TB + r * 4) * KR];
                GLOAD_LDS16(g, l);
            }
        }

        // 3) compute: broadcast ds_read_b128 of x, fma against wr in VGPRs
        const float* __restrict__ xq = &smem[(b * NWAVE + wq) * TB * KR];
#pragma unroll
        for (int t = 0; t < TB; ++t) {
            float a = acc[t];
            const float* __restrict__ xr = xq + t * KR;
#pragma unroll
            for (int j4 = 0; j4 < KR / 4; ++j4) {
                const float4 xv = *reinterpret_cast<const float4*>(&xr[j4 * 4]);
                a = fmaf(xv.x, wr[j4 * 4 + 0], a);
                a = fmaf(xv.y, wr[j4 * 4 + 1], a);
                a = fmaf(xv.z, wr[j4 * 4 + 2], a);
                a = fmaf(xv.w, wr[j4 * 4 + 3], a);
            }
            acc[t] = a;
        }
        __syncthreads();   // drains the prefetch (vmcnt) + protects buf reuse
    }

    // cross-wave reduction: reuse smem as red[NWAVE][TB][NE]
#pragma unroll
    for (int t = 0; t < TB; ++t) smem[(wq * TB + t) * NE + lane] = acc[t];
    __syncthreads();
    {
        const int e  = tid & 63;
        const int tg = tid >> 6;
        const float bia = rb[e];
#pragma unroll
        for (int i = 0; i < 4; ++i) {
            const int t = tg + i * 4;
            float v = (smem[(0 * TB + t) * NE + e] + smem[(1 * TB + t) * NE + e]) +
                      (smem[(2 * TB + t) * NE + e] + smem[(3 * TB + t) * NE + e]) + bia;
            smem[t * NE + e] = v;   // each (t,e) cell owned by exactly one thread
        }
    }
    __syncthreads();

    // top-2 (jax tie rule: ascending scan, strict >) + 2-way softmax
    if (tid < TB) {
        const int t = tid;
        float m1 = -INFINITY, m2 = -INFINITY;
        int i1 = 0, i2 = 0;
        for (int e = 0; e < NE; ++e) {
            float v = smem[t * NE + e];
            if (v > m1)      { m2 = m1; i2 = i1; m1 = v; i1 = e; }
            else if (v > m2) { m2 = v;  i2 = e; }
        }
        const float ed = expf(m2 - m1);
        const float p1 = 1.f / (1.f + ed);
        s_p1[t] = p1;
        s_p2[t] = 1.f - p1;
        s_i1[t] = i1;
        s_i2[t] = i2;
    }
    __syncthreads();

    // write router_output rows (every element, zeros included), float4 coalesced
    {
        const int t  = tid >> 4;
        const int c  = tid & 15;
        const int e0 = c * 4;
        const int i1 = s_i1[t], i2 = s_i2[t];
        const float p1 = s_p1[t], p2 = s_p2[t];
        float v[4];
#pragma unroll
        for (int j = 0; j < 4; ++j) {
            const int e = e0 + j;
            v[j] = (e == i1) ? p1 : ((e == i2) ? p2 : 0.f);
        }
        *reinterpret_cast<float4*>(out + (tok0 + t) * NE + e0) =
            make_float4(v[0], v[1], v[2], v[3]);
    }
    if (tid < TB) {
        float* idxo = out + (long)TOKENS * NE + (tok0 + tid) * 2;
        idxo[0] = (float)s_i1[tid];
        idxo[1] = (float)s_i2[tid];
    }
}

extern "C" void kernel_launch(void* const* d_in, const int* in_sizes, int n_in,
                              void* d_out, int out_size, void* d_ws, size_t ws_size,
                              hipStream_t stream) {
    const float* x       = (const float*)d_in[0];
    const float* route_w = (const float*)d_in[2];
    const float* route_b = (const float*)d_in[3];
    float* wt  = (float*)d_ws;
    float* out = (float*)d_out;

    hipLaunchKernelGGL(wt_transpose_kernel, dim3((EMB * NE) / 256), dim3(256), 0, stream,
                       route_w, wt);
    hipLaunchKernelGGL(router_kernel, dim3(TOKENS / TB), dim3(256), 0, stream,
                       x, wt, route_b, out);
}

// Round 4
// 148.871 us; speedup vs baseline: 3.4064x; 1.7847x over previous
//
#include <hip/hip_runtime.h>
#include <math.h>

// NoisyTopKRouter: out0 = softmax over top-2 of (x @ route_w^T + route_b) scattered
// into [16384,64]; out1 = top-2 indices (as floats). noise inputs are dead.
//
// R3: same structure as R2 (4x4 per-lane micro-tile, barrier-free counted-vmcnt
// K-loop, XOR-swizzled x reads with inverse-swizzled staging source).
// BUGFIX vs R2: read address was missing the token-group base (g*256); all
// lane-groups were reading tokens 0..7's LDS region.

#define TOKENS 16384
#define EMB    4096
#define NE     64
#define TB     32                 // tokens per block
#define NWAVES 8
#define KQ     (EMB / NWAVES)     // 512 k per wave (split-K)
#define KR     8                  // k per segment
#define NSEG   (KQ / KR)          // 64

#define GLOAD_LDS16(g, l)                                                      \
    __builtin_amdgcn_global_load_lds(                                          \
        (const __attribute__((address_space(1))) void*)(g),                    \
        (__attribute__((address_space(3))) void*)(l), 16, 0, 0)

// wt4[k][le][m] = route_w[le + 16*m][k]  (1 MB in d_ws; lane le reads its 4
// experts {le, le+16, le+32, le+48} for one k as a single float4)
__global__ __launch_bounds__(256) void wt4_prep_kernel(const float* __restrict__ w,
                                                       float* __restrict__ wt4) {
    int idx = blockIdx.x * 256 + threadIdx.x;   // over 4096*64, coalesced writes
    int k   = idx >> 6;
    int col = idx & 63;
    int le  = col >> 2;
    int m   = col & 3;
    wt4[idx] = w[(le + 16 * m) * EMB + k];
}

__global__ __launch_bounds__(512, 4) void router_kernel(const float* __restrict__ x,
                                                        const float* __restrict__ wt4,
                                                        const float* __restrict__ rb,
                                                        float* __restrict__ out) {
    __shared__ float xstage[NWAVES][2][KR * TB];   // 16 KB (1 KB per wave-buf)
    __shared__ float red[NWAVES][TB][NE];          // 64 KB partial logits

    const int tid  = threadIdx.x;
    const int lane = tid & 63;
    const int wq   = __builtin_amdgcn_readfirstlane(tid >> 6);
    const long tok0 = (long)blockIdx.x * TB;

    const int g   = lane >> 4;       // token group (reads tokens g*8..g*8+7)
    const int le  = lane & 15;       // expert lane (experts le + 16*m)
    const int swz = g << 4;          // byte XOR for swizzled x reads (bits 4..5)
    const int tbase = g * 256;       // token-group byte base (bits 8..9)

    // ---- staging source (inverse of the read-side XOR swizzle) ----
    // linear layout: token t at bytes [t*32, t*32+32), k-half h at +h*16.
    // read uses addr = (t*32 + h*16) ^ ((t>>3)<<4)  [bits 4..5 only]
    // lane l writes LDS bytes [l*16, l*16+16)  ->  slot token r_=l>>1, half hl=l&1
    // that slot is read by (t, h) with: t = r_ ^ bit0((r_>>4)), h = hl ^ ((r_>>3)&1)
    const int r_  = lane >> 1;
    const int hl  = lane & 1;
    const int t_s = r_ ^ ((r_ >> 4) & 1);
    const int h_s = hl ^ ((r_ >> 3) & 1);
    const float* xsrc = x + (tok0 + t_s) * (long)EMB + wq * KQ + 4 * h_s;

    // ---- w source: wt4 rows are 64 floats (256 B); lane offset le*4 ----
    const float* wsrc = wt4 + (long)(wq * KQ) * NE + le * 4;

    float acc[8][4];
#pragma unroll
    for (int i = 0; i < 8; ++i)
#pragma unroll
        for (int m = 0; m < 4; ++m) acc[i][m] = 0.f;

    float* lds0 = &xstage[wq][0][0];
    float* lds1 = &xstage[wq][1][0];

    // prologue: stage seg 0
    GLOAD_LDS16(xsrc, lds0);

    auto compute_seg = [&](const float* __restrict__ wseg,
                           const char* __restrict__ xb) {
        float w4a[KR][4];
#pragma unroll
        for (int k = 0; k < KR; ++k)
            *reinterpret_cast<float4*>(&w4a[k][0]) =
                *reinterpret_cast<const float4*>(wseg + k * NE);
#pragma unroll
        for (int i = 0; i < 8; ++i) {
            const float4 xa = *reinterpret_cast<const float4*>(xb + ((tbase + i * 32 + 0)  ^ swz));
            const float4 xc = *reinterpret_cast<const float4*>(xb + ((tbase + i * 32 + 16) ^ swz));
#pragma unroll
            for (int m = 0; m < 4; ++m) {
                float a = acc[i][m];
                a = fmaf(xa.x, w4a[0][m], a);
                a = fmaf(xa.y, w4a[1][m], a);
                a = fmaf(xa.z, w4a[2][m], a);
                a = fmaf(xa.w, w4a[3][m], a);
                a = fmaf(xc.x, w4a[4][m], a);
                a = fmaf(xc.y, w4a[5][m], a);
                a = fmaf(xc.z, w4a[6][m], a);
                a = fmaf(xc.w, w4a[7][m], a);
                acc[i][m] = a;
            }
        }
    };

    for (int s = 0; s < NSEG - 1; ++s) {
        const int b = s & 1;
        // stage next seg into the other buffer (stays in flight during compute)
        GLOAD_LDS16(xsrc + (s + 1) * KR, (b ? lds0 : lds1));
        // wait until at most the newest stage is outstanding -> stage(s) done
        asm volatile("s_waitcnt vmcnt(1)" ::: "memory");
        compute_seg(wsrc + (long)s * KR * NE,
                    (const char*)(b ? lds1 : lds0));
    }
    {   // final segment
        const int b = (NSEG - 1) & 1;
        asm volatile("s_waitcnt vmcnt(0)" ::: "memory");
        compute_seg(wsrc + (long)(NSEG - 1) * KR * NE,
                    (const char*)(b ? lds1 : lds0));
    }

    // ---- cross-wave reduction ----
#pragma unroll
    for (int i = 0; i < 8; ++i)
#pragma unroll
        for (int m = 0; m < 4; ++m)
            red[wq][g * 8 + i][le + 16 * m] = acc[i][m];
    __syncthreads();

    float* lg = &xstage[0][0][0];   // reuse staging region: 2048 + 128 floats
    {
        const int t  = tid >> 4;        // 0..31
        const int e0 = (tid & 15) * 4;
        float4 sum = *reinterpret_cast<const float4*>(rb + e0);
#pragma unroll
        for (int w = 0; w < NWAVES; ++w) {
            const float4 p = *reinterpret_cast<const float4*>(&red[w][t][e0]);
            sum.x += p.x; sum.y += p.y; sum.z += p.z; sum.w += p.w;
        }
        *reinterpret_cast<float4*>(&lg[t * NE + e0]) = sum;
    }
    __syncthreads();

    // top-2 (jax tie rule: ascending scan, strict >) + 2-way softmax
    if (tid < TB) {
        const int t = tid;
        float m1 = -INFINITY, m2 = -INFINITY;
        int i1 = 0, i2 = 0;
        for (int e = 0; e < NE; ++e) {
            float v = lg[t * NE + e];
            if (v > m1)      { m2 = m1; i2 = i1; m1 = v; i1 = e; }
            else if (v > m2) { m2 = v;  i2 = e; }
        }
        const float ed = expf(m2 - m1);
        const float p1 = 1.f / (1.f + ed);
        lg[2048 + t]       = p1;            // P1
        lg[2048 + 32 + t]  = 1.f - p1;      // P2
        lg[2048 + 64 + t]  = (float)i1;     // I1
        lg[2048 + 96 + t]  = (float)i2;     // I2
    }
    __syncthreads();

    // write router_output rows (every element, zeros included), float4 coalesced
    {
        const int t  = tid >> 4;
        const int e0 = (tid & 15) * 4;
        const int i1 = (int)lg[2048 + 64 + t];
        const int i2 = (int)lg[2048 + 96 + t];
        const float p1 = lg[2048 + t];
        const float p2 = lg[2048 + 32 + t];
        float v[4];
#pragma unroll
        for (int j = 0; j < 4; ++j) {
            const int e = e0 + j;
            v[j] = (e == i1) ? p1 : ((e == i2) ? p2 : 0.f);
        }
        *reinterpret_cast<float4*>(out + (tok0 + t) * NE + e0) =
            make_float4(v[0], v[1], v[2], v[3]);
    }
    if (tid < TB) {
        float* idxo = out + (long)TOKENS * NE + (tok0 + tid) * 2;
        idxo[0] = lg[2048 + 64 + tid];
        idxo[1] = lg[2048 + 96 + tid];
    }
}

extern "C" void kernel_launch(void* const* d_in, const int* in_sizes, int n_in,
                              void* d_out, int out_size, void* d_ws, size_t ws_size,
                              hipStream_t stream) {
    const float* x       = (const float*)d_in[0];
    const float* route_w = (const float*)d_in[2];
    const float* route_b = (const float*)d_in[3];
    float* wt4 = (float*)d_ws;          // 1 MB scratch
    float* out = (float*)d_out;

    hipLaunchKernelGGL(wt4_prep_kernel, dim3((EMB * NE) / 256), dim3(256), 0, stream,
                       route_w, wt4);
    hipLaunchKernelGGL(router_kernel, dim3(TOKENS / TB), dim3(512), 0, stream,
                       x, wt4, route_b, out);
}